// Round 11
// baseline (113.690 us; speedup 1.0000x reference)
//
#include <hip/hip_runtime.h>

typedef __bf16 bf16x8 __attribute__((ext_vector_type(8)));
typedef float f32x4 __attribute__((ext_vector_type(4)));
typedef float f32x16 __attribute__((ext_vector_type(16)));

#define S_LEN 2048
#define D_DIM 64
#define NHEAD 32
#define PART_FLOATS 8448   // 128 m + 128 l + 128*64 acc

typedef __attribute__((address_space(1))) const void gas;
typedef __attribute__((address_space(3))) void las;

#define J(c, t0, nt) ((unsigned short)((c) | ((t0) << 4) | ((nt) << 9)))

// MODE 0: 40 jobs/head (segments <= 8 tiles), 8 CU-groups x 5 passes.
// Each group: sum = 34 tiles, max job = 8 tiles. All 5 jobs co-resident on one CU.
__device__ const unsigned short JOBS5[40] = {
    J(15,0,8), J(15,8,8), J(15,16,8), J(15,24,8), J(0,0,2),
    J(14,0,8), J(14,8,8), J(14,16,8), J(13,16,8), J(4,8,2),
    J(13,0,8), J(13,8,8), J(12,16,8), J(12,8,8),  J(8,16,2),
    J(12,0,8), J(11,16,8),J(11,8,8),  J(11,0,8),  J(12,24,2),
    J(10,0,8), J(10,8,8), J(9,8,8),   J(1,0,4),   J(10,16,6),
    J(9,0,8),  J(8,8,8),  J(8,0,8),   J(5,8,4),   J(14,24,6),
    J(7,8,8),  J(7,0,8),  J(6,0,8),   J(9,16,4),  J(6,8,6),
    J(5,0,8),  J(4,0,8),  J(3,0,8),   J(13,24,4), J(2,0,6),
};
// partial-slot prefix for chunks 4..15 (nseg = 2,2,2,2,3,3,3,3,4,4,4,4; total 36)
__device__ const int PRE[12]  = {0,2,4,6,8,11,14,17,20,24,28,32};
__device__ const int NSEG[12] = {2,2,2,2,3,3,3,3,4,4,4,4};

// MODE 1: 24 jobs/head, 8 CU-triples of 34 tiles (round-10 schedule).
__device__ const unsigned short TRIP[24] = {
    J(15,0,16), J(15,16,16), J(0,0,2),
    J(7,0,16),  J(13,0,14),  J(1,0,4),
    J(14,0,15), J(12,0,13),  J(2,0,6),
    J(14,15,15),J(10,0,11),  J(3,0,8),
    J(13,14,14),J(10,11,11), J(8,0,9),
    J(6,0,14),  J(9,0,10),   J(9,10,10),
    J(12,13,13),J(11,0,12),  J(8,9,9),
    J(11,12,12),J(5,0,12),   J(4,0,10),
};

// ---------------- pre-pass: K -> bf16 [h][s][d], V -> bf16 transposed [h][d][s] ----------------
__global__ __launch_bounds__(256) void convert_kv(const float* __restrict__ K,
                                                  const float* __restrict__ V,
                                                  __bf16* __restrict__ Kb,
                                                  __bf16* __restrict__ Vtg) {
    const int head = blockIdx.y;
    const int s0   = blockIdx.x * 64;
    const int tr   = threadIdx.x >> 2;
    const int tc   = (threadIdx.x & 3) << 4;
    const size_t ib = (size_t)head * (S_LEN * D_DIM) + (size_t)(s0 + tr) * D_DIM + tc;

    __shared__ __bf16 tb[64][72];

    {   // K: straight convert
        const float* kr = K + ib;
        f32x4 a = *(const f32x4*)kr, b = *(const f32x4*)(kr + 4),
              c = *(const f32x4*)(kr + 8), d = *(const f32x4*)(kr + 12);
        bf16x8 o0, o1;
        #pragma unroll
        for (int e = 0; e < 4; ++e) {
            o0[e] = (__bf16)a[e]; o0[e + 4] = (__bf16)b[e];
            o1[e] = (__bf16)c[e]; o1[e + 4] = (__bf16)d[e];
        }
        __bf16* ko = Kb + ib;
        *(bf16x8*)ko = o0; *(bf16x8*)(ko + 8) = o1;
    }
    {   // V: transpose 64x64 tile via LDS
        const float* vr = V + ib;
        f32x4 a = *(const f32x4*)vr, b = *(const f32x4*)(vr + 4),
              c = *(const f32x4*)(vr + 8), d = *(const f32x4*)(vr + 12);
        #pragma unroll
        for (int e = 0; e < 4; ++e) {
            tb[tc +  e][tr] = (__bf16)a[e];
            tb[tc + 4 + e][tr] = (__bf16)b[e];
            tb[tc + 8 + e][tr] = (__bf16)c[e];
            tb[tc + 12 + e][tr] = (__bf16)d[e];
        }
    }
    __syncthreads();
    {
        bf16x8 o0, o1;
        #pragma unroll
        for (int e = 0; e < 8; ++e) { o0[e] = tb[tr][tc + e]; o1[e] = tb[tr][tc + 8 + e]; }
        __bf16* vo = Vtg + (size_t)head * (D_DIM * S_LEN) + (size_t)tr * S_LEN + s0 + tc;
        *(bf16x8*)vo = o0; *(bf16x8*)(vo + 8) = o1;
    }
}

// ---------------- main: 32x32 MFMA flash attention, in-register P (T12) ----------------
template <int MODE>
__global__ __launch_bounds__(256, MODE == 0 ? 5 : 3)
void attn32(const float* __restrict__ Q,
            const __bf16* __restrict__ Kb,
            const __bf16* __restrict__ Vg,
            float* __restrict__ O,
            float* __restrict__ Pp) {
    const int b    = blockIdx.x;
    const int xcd  = b & 7;
    const int cu   = (b >> 3) & 31;
    const int pass = b >> 8;                  // MODE0: 0..4, MODE1: 0..2
    const int head = xcd * 4 + (cu >> 3);     // 4 heads per XCD
    const unsigned short jw = (MODE == 0) ? JOBS5[(cu & 7) * 5 + pass]
                                          : TRIP[(cu & 7) * 3 + pass];
    const int chunk = jw & 15;                // 128-row q-chunk
    const int t0    = (jw >> 4) & 31;         // first 64-key tile
    const int nt    = jw >> 9;                // tile count

    const int tid  = threadIdx.x;
    const int wave = tid >> 6;
    const int lane = tid & 63;
    const int l31  = lane & 31;
    const int hi   = lane >> 5;
    const int sw31 = (l31 & 7) << 3;

    const int q0w = chunk * 128 + wave * 32;  // wave owns q rows q0w..q0w+31
    const size_t qbase = (size_t)head * (S_LEN * D_DIM);
    const size_t vbase = (size_t)head * (D_DIM * S_LEN);
    const float qscale = 0.125f * 1.44269504088896340736f;   // D^-0.5 * log2(e)

    __shared__ __align__(16) __bf16 Klds[2][64][64];   // [buf][key][d], 16B-unit col ^ (key&7)
    __shared__ __align__(16) __bf16 Vt[2][64][64];     // [buf][d][key], 16B-unit col ^ (d&7)

    // per-lane pre-swizzled gload_lds source offsets
    const int xsw = (lane & 7) ^ ((lane >> 3) & 7);
    const size_t kOff = (size_t)(lane >> 3) * D_DIM + (size_t)xsw * 8;
    const size_t vOff = (size_t)(lane >> 3) * S_LEN + (size_t)xsw * 8;
    const __bf16* kgw = Kb + qbase + (size_t)(wave * 16) * D_DIM + kOff;
    const __bf16* vgw = Vg + vbase + (size_t)(wave * 16) * S_LEN + vOff;

    // ---- Q B-frags (swapped QK^T): col=q=l31, k-dim d = kd*16 + hi*8 + e ----
    bf16x8 qf[4];
    {
        const float* qrow = Q + qbase + (size_t)(q0w + l31) * D_DIM + hi * 8;
        #pragma unroll
        for (int kd = 0; kd < 4; ++kd) {
            f32x4 a = *(const f32x4*)(qrow + kd * 16);
            f32x4 c = *(const f32x4*)(qrow + kd * 16 + 4);
            bf16x8 t;
            #pragma unroll
            for (int e = 0; e < 4; ++e) { t[e] = (__bf16)(a[e] * qscale); t[e + 4] = (__bf16)(c[e] * qscale); }
            qf[kd] = t;
        }
    }

    f32x16 acc0, acc1;                        // O[q=crow(r,hi)][d = l31 (+32 for acc1)]
    #pragma unroll
    for (int r = 0; r < 16; ++r) { acc0[r] = 0.f; acc1[r] = 0.f; }
    float m_r = -1e30f, l_r = 0.f;            // per-lane: q-row = q0w + l31

    auto stage = [&](int kv0, int bufi) {
        const __bf16* kg = kgw + (size_t)kv0 * D_DIM;
        const __bf16* vg = vgw + kv0;
        __builtin_amdgcn_global_load_lds((gas*)kg,               (las*)&Klds[bufi][wave * 16][0],     16, 0, 0);
        __builtin_amdgcn_global_load_lds((gas*)(kg + 8 * D_DIM), (las*)&Klds[bufi][wave * 16 + 8][0], 16, 0, 0);
        __builtin_amdgcn_global_load_lds((gas*)vg,               (las*)&Vt[bufi][wave * 16][0],       16, 0, 0);
        __builtin_amdgcn_global_load_lds((gas*)(vg + 8 * S_LEN), (las*)&Vt[bufi][wave * 16 + 8][0],   16, 0, 0);
    };
    auto cvtpk = [](float lo, float hh) {
        unsigned int r;
        asm("v_cvt_pk_bf16_f32 %0, %1, %2" : "=v"(r) : "v"(lo), "v"(hh));
        return r;
    };

    stage(t0 << 6, 0);

    for (int it = 0; it < nt; ++it) {
        const int cur = it & 1;
        asm volatile("s_waitcnt vmcnt(0)" ::: "memory");
        __syncthreads();                      // buf[cur] fully staged by all waves

        if (it + 1 < nt) stage((t0 + it + 1) << 6, cur ^ 1);
        const int kv0 = (t0 + it) << 6;

        if (kv0 <= q0w + 31) {                // wave has unmasked work this tile
            // ---- S^T = K Q^T (32x32): lane holds 32 scores of q-row q0w+l31 ----
            f32x16 s0, s1;
            #pragma unroll
            for (int r = 0; r < 16; ++r) { s0[r] = 0.f; s1[r] = 0.f; }
            __builtin_amdgcn_s_setprio(1);
            #pragma unroll
            for (int kd = 0; kd < 4; ++kd) {
                bf16x8 kf0 = *(const bf16x8*)&Klds[cur][l31][(kd * 16 + hi * 8) ^ sw31];
                bf16x8 kf1 = *(const bf16x8*)&Klds[cur][32 + l31][(kd * 16 + hi * 8) ^ sw31];
                s0 = __builtin_amdgcn_mfma_f32_32x32x16_bf16(kf0, qf[kd], s0, 0, 0, 0);
                s1 = __builtin_amdgcn_mfma_f32_32x32x16_bf16(kf1, qf[kd], s1, 0, 0, 0);
            }
            __builtin_amdgcn_s_setprio(0);

            // ---- causal mask (diagonal-straddling tiles only) ----
            if (kv0 + 63 > q0w) {
                const int qg = q0w + l31;
                #pragma unroll
                for (int r = 0; r < 16; ++r) {
                    const int cr = (r & 3) + 8 * (r >> 2) + 4 * hi;
                    if (kv0 + cr > qg)      s0[r] = -1e30f;
                    if (kv0 + 32 + cr > qg) s1[r] = -1e30f;
                }
            }

            // ---- in-lane online softmax; tree reductions (depth 5) ----
            float t[16];
            #pragma unroll
            for (int r = 0; r < 16; ++r) t[r] = fmaxf(s0[r], s1[r]);
            #pragma unroll
            for (int off = 8; off >= 1; off >>= 1)
                #pragma unroll
                for (int r = 0; r < 16; ++r) if (r < off) t[r] = fmaxf(t[r], t[r + off]);
            float mm = fmaxf(t[0], __shfl_xor(t[0], 32));
            if (!__all(mm - m_r <= 8.0f)) {   // defer-max: rescale rarely
                const float mn = fmaxf(m_r, mm);
                const float f = exp2f(m_r - mn);
                m_r = mn;
                l_r *= f;
                #pragma unroll
                for (int r = 0; r < 16; ++r) {
                    const float fr = __shfl(f, (r & 3) + 8 * (r >> 2) + 4 * hi);
                    acc0[r] *= fr; acc1[r] *= fr;
                }
            }
            float u[16];
            #pragma unroll
            for (int r = 0; r < 16; ++r) {
                s0[r] = exp2f(s0[r] - m_r);
                s1[r] = exp2f(s1[r] - m_r);
                u[r] = s0[r] + s1[r];
            }
            #pragma unroll
            for (int off = 8; off >= 1; off >>= 1)
                #pragma unroll
                for (int r = 0; r < 16; ++r) if (r < off) u[r] += u[r + off];
            l_r += u[0] + __shfl_xor(u[0], 32);

            // ---- P -> A-frags in-register (T12: cvt_pk + permlane32_swap), then PV ----
            __builtin_amdgcn_s_setprio(1);
            {   // keys kv0..+31
                unsigned int w01 = cvtpk(s0[0],  s0[1]),  w23 = cvtpk(s0[2],  s0[3]);
                unsigned int w45 = cvtpk(s0[4],  s0[5]),  w67 = cvtpk(s0[6],  s0[7]);
                unsigned int w89 = cvtpk(s0[8],  s0[9]),  wab = cvtpk(s0[10], s0[11]);
                unsigned int wcd = cvtpk(s0[12], s0[13]), wef = cvtpk(s0[14], s0[15]);
                asm("v_permlane32_swap_b32 %0, %1" : "+v"(w01), "+v"(w45));
                asm("v_permlane32_swap_b32 %0, %1" : "+v"(w23), "+v"(w67));
                asm("v_permlane32_swap_b32 %0, %1" : "+v"(w89), "+v"(wcd));
                asm("v_permlane32_swap_b32 %0, %1" : "+v"(wab), "+v"(wef));
                union { unsigned int u[4]; bf16x8 v; } f0 = {{w01, w23, w45, w67}};
                union { unsigned int u[4]; bf16x8 v; } f1 = {{w89, wab, wcd, wef}};
                bf16x8 v00 = *(const bf16x8*)&Vt[cur][l31][(hi * 8) ^ sw31];
                bf16x8 v01 = *(const bf16x8*)&Vt[cur][32 + l31][(hi * 8) ^ sw31];
                acc0 = __builtin_amdgcn_mfma_f32_32x32x16_bf16(f0.v, v00, acc0, 0, 0, 0);
                acc1 = __builtin_amdgcn_mfma_f32_32x32x16_bf16(f0.v, v01, acc1, 0, 0, 0);
                bf16x8 v10 = *(const bf16x8*)&Vt[cur][l31][(16 + hi * 8) ^ sw31];
                bf16x8 v11 = *(const bf16x8*)&Vt[cur][32 + l31][(16 + hi * 8) ^ sw31];
                acc0 = __builtin_amdgcn_mfma_f32_32x32x16_bf16(f1.v, v10, acc0, 0, 0, 0);
                acc1 = __builtin_amdgcn_mfma_f32_32x32x16_bf16(f1.v, v11, acc1, 0, 0, 0);
            }
            {   // keys kv0+32..+63
                unsigned int w01 = cvtpk(s1[0],  s1[1]),  w23 = cvtpk(s1[2],  s1[3]);
                unsigned int w45 = cvtpk(s1[4],  s1[5]),  w67 = cvtpk(s1[6],  s1[7]);
                unsigned int w89 = cvtpk(s1[8],  s1[9]),  wab = cvtpk(s1[10], s1[11]);
                unsigned int wcd = cvtpk(s1[12], s1[13]), wef = cvtpk(s1[14], s1[15]);
                asm("v_permlane32_swap_b32 %0, %1" : "+v"(w01), "+v"(w45));
                asm("v_permlane32_swap_b32 %0, %1" : "+v"(w23), "+v"(w67));
                asm("v_permlane32_swap_b32 %0, %1" : "+v"(w89), "+v"(wcd));
                asm("v_permlane32_swap_b32 %0, %1" : "+v"(wab), "+v"(wef));
                union { unsigned int u[4]; bf16x8 v; } f2 = {{w01, w23, w45, w67}};
                union { unsigned int u[4]; bf16x8 v; } f3 = {{w89, wab, wcd, wef}};
                bf16x8 v20 = *(const bf16x8*)&Vt[cur][l31][(32 + hi * 8) ^ sw31];
                bf16x8 v21 = *(const bf16x8*)&Vt[cur][32 + l31][(32 + hi * 8) ^ sw31];
                acc0 = __builtin_amdgcn_mfma_f32_32x32x16_bf16(f2.v, v20, acc0, 0, 0, 0);
                acc1 = __builtin_amdgcn_mfma_f32_32x32x16_bf16(f2.v, v21, acc1, 0, 0, 0);
                bf16x8 v30 = *(const bf16x8*)&Vt[cur][l31][(48 + hi * 8) ^ sw31];
                bf16x8 v31 = *(const bf16x8*)&Vt[cur][32 + l31][(48 + hi * 8) ^ sw31];
                acc0 = __builtin_amdgcn_mfma_f32_32x32x16_bf16(f3.v, v30, acc0, 0, 0, 0);
                acc1 = __builtin_amdgcn_mfma_f32_32x32x16_bf16(f3.v, v31, acc1, 0, 0, 0);
            }
            __builtin_amdgcn_s_setprio(0);
        }
    }

    // ---- epilogue ----
    const bool direct = (MODE == 0) ? (chunk < 4) : (chunk < 8);
    if (direct) {                             // unsplit chunk: O = acc / l
        const float inv_own = 1.0f / l_r;
        float* ob = O + qbase + (size_t)(chunk * 128 + wave * 32) * D_DIM + l31;
        #pragma unroll
        for (int r = 0; r < 16; ++r) {
            const int cr = (r & 3) + 8 * (r >> 2) + 4 * hi;
            const float inv = __shfl(inv_own, cr);
            ob[(size_t)cr * D_DIM]      = acc0[r] * inv;
            ob[(size_t)cr * D_DIM + 32] = acc1[r] * inv;
        }
    } else {                                  // split segment: raw fp32 partials
        size_t slot;
        if (MODE == 0) slot = (size_t)head * 36 + PRE[chunk - 4] + (t0 >> 3);
        else           slot = (size_t)((head * 8 + (chunk - 8)) * 2 + (t0 != 0 ? 1 : 0));
        float* pp = Pp + slot * PART_FLOATS;
        if (hi == 0) {
            pp[wave * 32 + l31] = m_r;
            pp[128 + wave * 32 + l31] = l_r;
        }
        float* pb = pp + 256 + (size_t)(wave * 32) * 64 + l31;
        #pragma unroll
        for (int r = 0; r < 16; ++r) {
            const int cr = (r & 3) + 8 * (r >> 2) + 4 * hi;
            pb[(size_t)cr * 64]      = acc0[r];
            pb[(size_t)cr * 64 + 32] = acc1[r];
        }
    }
}

// ---------------- combine ----------------
// MODE 0: chunks 4..15, 2..4 segments each. MODE 1: chunks 8..15, 2 segments.
template <int MODE>
__global__ __launch_bounds__(256) void combine(const float* __restrict__ Pp,
                                               float* __restrict__ O) {
    const int head = blockIdx.y;
    const int bx   = blockIdx.x;
    const int ch   = (MODE == 0) ? (4 + bx) : (8 + bx);
    const int ns   = (MODE == 0) ? NSEG[bx] : 2;
    const size_t base = (MODE == 0) ? ((size_t)head * 36 + PRE[bx])
                                    : (size_t)((head * 8 + bx) * 2);
    const int row = threadIdx.x >> 1;          // 0..127
    const int c0  = (threadIdx.x & 1) << 5;    // 0, 32

    float m[4], l[4], w[4];
    float M = -1e30f;
    #pragma unroll
    for (int s = 0; s < 4; ++s)
        if (s < ns) {
            const float* P = Pp + (base + s) * PART_FLOATS;
            m[s] = P[row]; l[s] = P[128 + row];
            M = fmaxf(M, m[s]);
        }
    float L = 0.f;
    #pragma unroll
    for (int s = 0; s < 4; ++s)
        if (s < ns) { w[s] = exp2f(m[s] - M); L += l[s] * w[s]; }
    const float inv = 1.0f / L;

    float* o = O + (size_t)head * (S_LEN * D_DIM) + (size_t)(ch * 128 + row) * D_DIM + c0;
    #pragma unroll
    for (int i = 0; i < 8; ++i) {
        f32x4 vo = (f32x4){0.f, 0.f, 0.f, 0.f};
        #pragma unroll
        for (int s = 0; s < 4; ++s)
            if (s < ns) {
                const float* a = Pp + (base + s) * PART_FLOATS + 256 + (size_t)row * 64 + c0;
                f32x4 va = *(const f32x4*)(a + 4 * i);
                #pragma unroll
                for (int e = 0; e < 4; ++e) vo[e] += va[e] * w[s];
            }
        #pragma unroll
        for (int e = 0; e < 4; ++e) vo[e] *= inv;
        *(f32x4*)(o + 4 * i) = vo;
    }
}

// ---------------- fallback (fp32 in-kernel staging, proven) if ws too small ----------------
__global__ __launch_bounds__(256, 4) void attn_fwd_fb(const float* __restrict__ Q,
                                                      const float* __restrict__ K,
                                                      const float* __restrict__ V,
                                                      float* __restrict__ O) {
    const int b    = blockIdx.x;
    const int xcd  = b & 7;
    const int cs   = (b >> 3) & 31;
    const int j    = b >> 8;
    const int head = xcd * 4 + (cs >> 3);
    const int slot = cs & 7;
    const int chunk = (j == 0) ? slot : (j == 1) ? (31 - slot)
                    : (j == 2) ? (slot + 8) : (23 - slot);

    const int tid  = threadIdx.x;
    const int wave = tid >> 6;
    const int lane = tid & 63;
    const int l15  = lane & 15;
    const int lhi  = lane >> 4;

    const int q0 = chunk * 64 + wave * 16;
    const size_t base = (size_t)head * (S_LEN * D_DIM);
    const float qscale = 0.125f * 1.44269504088896340736f;

    __shared__ __align__(16) __bf16 Klds[2][64][64];
    __shared__ __align__(16) __bf16 Vt[2][64][64];
    __shared__ __align__(16) __bf16 Plds[4][16][64];

    const int rk = tid >> 2;
    const int ck = (tid & 3) << 4;
    const int kp = tid & 31;
    const int dc = tid >> 5;
    const int swk = (rk & 7) << 3;

    bf16x8 qf[2];
    {
        const float* qrow = Q + base + (size_t)(q0 + l15) * D_DIM + lhi * 8;
        #pragma unroll
        for (int h = 0; h < 2; ++h) {
            f32x4 a = *(const f32x4*)(qrow + h * 32);
            f32x4 bq = *(const f32x4*)(qrow + h * 32 + 4);
            bf16x8 t;
            #pragma unroll
            for (int e = 0; e < 4; ++e) { t[e] = (__bf16)(a[e] * qscale); t[e + 4] = (__bf16)(bq[e] * qscale); }
            qf[h] = t;
        }
    }

    f32x4 acc[4];
    #pragma unroll
    for (int td = 0; td < 4; ++td) acc[td] = (f32x4){0.f, 0.f, 0.f, 0.f};
    float m_r = -1e30f, l_r = 0.f;

    f32x4 pk[4], pva[2], pvb[2];
    {
        const float* ks = K + base + (size_t)rk * D_DIM + ck;
        #pragma unroll
        for (int i = 0; i < 4; ++i) pk[i] = *(const f32x4*)(ks + 4 * i);
        const float* v0 = V + base + (size_t)(2 * kp) * D_DIM + dc * 8;
        pva[0] = *(const f32x4*)v0;           pva[1] = *(const f32x4*)(v0 + 4);
        pvb[0] = *(const f32x4*)(v0 + D_DIM); pvb[1] = *(const f32x4*)(v0 + D_DIM + 4);
        bf16x8 k0, k1;
        #pragma unroll
        for (int e = 0; e < 4; ++e) {
            k0[e] = (__bf16)pk[0][e]; k0[e + 4] = (__bf16)pk[1][e];
            k1[e] = (__bf16)pk[2][e]; k1[e + 4] = (__bf16)pk[3][e];
        }
        *(bf16x8*)&Klds[0][rk][ck ^ swk] = k0;
        *(bf16x8*)&Klds[0][rk][(ck + 8) ^ swk] = k1;
        #pragma unroll
        for (int jj = 0; jj < 8; ++jj) {
            const int d = dc * 8 + jj;
            const float av = (jj < 4) ? pva[0][jj & 3] : pva[1][jj & 3];
            const float bv = (jj < 4) ? pvb[0][jj & 3] : pvb[1][jj & 3];
            union { __bf16 h[2]; unsigned int u; } t;
            t.h[0] = (__bf16)av; t.h[1] = (__bf16)bv;
            *(unsigned int*)&Vt[0][d][(2 * kp) ^ ((d & 7) << 3)] = t.u;
        }
    }

    const int nt = chunk + 1;
    for (int kt = 0; kt < nt; ++kt) {
        const int cur = kt & 1;
        __syncthreads();
        const bool pre = (kt + 1 < nt);
        if (pre) {
            const int kv1 = (kt + 1) << 6;
            const float* ks = K + base + (size_t)(kv1 + rk) * D_DIM + ck;
            #pragma unroll
            for (int i = 0; i < 4; ++i) pk[i] = *(const f32x4*)(ks + 4 * i);
            const float* v0 = V + base + (size_t)(kv1 + 2 * kp) * D_DIM + dc * 8;
            pva[0] = *(const f32x4*)v0;           pva[1] = *(const f32x4*)(v0 + 4);
            pvb[0] = *(const f32x4*)(v0 + D_DIM); pvb[1] = *(const f32x4*)(v0 + D_DIM + 4);
        }

        f32x4 s[4];
        #pragma unroll
        for (int ct = 0; ct < 4; ++ct) s[ct] = (f32x4){0.f, 0.f, 0.f, 0.f};
        #pragma unroll
        for (int h = 0; h < 2; ++h) {
            #pragma unroll
            for (int ct = 0; ct < 4; ++ct) {
                const int krow = ct * 16 + l15;
                bf16x8 kf = *(const bf16x8*)&Klds[cur][krow][(h * 32 + lhi * 8) ^ ((l15 & 7) << 3)];
                s[ct] = __builtin_amdgcn_mfma_f32_16x16x32_bf16(kf, qf[h], s[ct], 0, 0, 0);
            }
        }

        if (kt == nt - 1) {
            const int kv0 = kt << 6;
            const int qg = q0 + l15;
            #pragma unroll
            for (int ct = 0; ct < 4; ++ct)
                #pragma unroll
                for (int r = 0; r < 4; ++r) {
                    const int kg = kv0 + ct * 16 + lhi * 4 + r;
                    if (kg > qg) s[ct][r] = -1e30f;
                }
        }

        float mm = fmaxf(fmaxf(fmaxf(s[0][0], s[0][1]), fmaxf(s[0][2], s[0][3])),
                         fmaxf(fmaxf(s[1][0], s[1][1]), fmaxf(s[1][2], s[1][3])));
        mm = fmaxf(mm, fmaxf(fmaxf(fmaxf(s[2][0], s[2][1]), fmaxf(s[2][2], s[2][3])),
                             fmaxf(fmaxf(s[3][0], s[3][1]), fmaxf(s[3][2], s[3][3]))));
        mm = fmaxf(mm, __shfl_xor(mm, 16));
        mm = fmaxf(mm, __shfl_xor(mm, 32));
        if (!__all(mm - m_r <= 8.0f)) {
            const float mn = fmaxf(m_r, mm);
            const float f = exp2f(m_r - mn);
            m_r = mn;
            l_r *= f;
            #pragma unroll
            for (int r = 0; r < 4; ++r) {
                const float fr = __shfl(f, lhi * 4 + r);
                #pragma unroll
                for (int td = 0; td < 4; ++td) acc[td][r] *= fr;
            }
        }
        float ps = 0.f;
        #pragma unroll
        for (int ct = 0; ct < 4; ++ct)
            #pragma unroll
            for (int r = 0; r < 4; ++r) {
                const float p = exp2f(s[ct][r] - m_r);
                s[ct][r] = p;
                ps += p;
            }
        ps += __shfl_xor(ps, 16);
        ps += __shfl_xor(ps, 32);
        l_r += ps;

        #pragma unroll
        for (int ct = 0; ct < 4; ++ct) {
            union { __bf16 h[4]; unsigned long long u; } pw;
            #pragma unroll
            for (int r = 0; r < 4; ++r) pw.h[r] = (__bf16)s[ct][r];
            *(unsigned long long*)&Plds[wave][l15][(ct * 16 + lhi * 4) ^ ((l15 & 7) << 3)] = pw.u;
        }
        asm volatile("s_waitcnt lgkmcnt(0)" ::: "memory");
        bf16x8 pf[2];
        #pragma unroll
        for (int kh = 0; kh < 2; ++kh)
            pf[kh] = *(const bf16x8*)&Plds[wave][l15][(kh * 32 + lhi * 8) ^ ((l15 & 7) << 3)];
        asm volatile("" ::: "memory");

        #pragma unroll
        for (int kh = 0; kh < 2; ++kh) {
            #pragma unroll
            for (int td = 0; td < 4; ++td) {
                const int vrow = td * 16 + l15;
                bf16x8 vf = *(const bf16x8*)&Vt[cur][vrow][(kh * 32 + lhi * 8) ^ ((vrow & 7) << 3)];
                acc[td] = __builtin_amdgcn_mfma_f32_16x16x32_bf16(pf[kh], vf, acc[td], 0, 0, 0);
            }
        }

        if (pre) {
            const int nxt = cur ^ 1;
            bf16x8 k0, k1;
            #pragma unroll
            for (int e = 0; e < 4; ++e) {
                k0[e] = (__bf16)pk[0][e]; k0[e + 4] = (__bf16)pk[1][e];
                k1[e] = (__bf16)pk[2][e]; k1[e + 4] = (__bf16)pk[3][e];
            }
            *(bf16x8*)&Klds[nxt][rk][ck ^ swk] = k0;
            *(bf16x8*)&Klds[nxt][rk][(ck + 8) ^ swk] = k1;
            #pragma unroll
            for (int jj = 0; jj < 8; ++jj) {
                const int d = dc * 8 + jj;
                const float av = (jj < 4) ? pva[0][jj & 3] : pva[1][jj & 3];
                const float bv = (jj < 4) ? pvb[0][jj & 3] : pvb[1][jj & 3];
                union { __bf16 h[2]; unsigned int u; } t;
                t.h[0] = (__bf16)av; t.h[1] = (__bf16)bv;
                *(unsigned int*)&Vt[nxt][d][(2 * kp) ^ ((d & 7) << 3)] = t.u;
            }
        }
    }

    float* orow = O + base + (size_t)q0 * D_DIM;
    #pragma unroll
    for (int r = 0; r < 4; ++r) {
        const float inv = 1.0f / __shfl(l_r, lhi * 4 + r);
        #pragma unroll
        for (int td = 0; td < 4; ++td)
            orow[(size_t)(lhi * 4 + r) * D_DIM + td * 16 + l15] = acc[td][r] * inv;
    }
}

extern "C" void kernel_launch(void* const* d_in, const int* in_sizes, int n_in,
                              void* d_out, int out_size, void* d_ws, size_t ws_size,
                              hipStream_t stream) {
    const float* q = (const float*)d_in[0];
    const float* k = (const float*)d_in[1];
    const float* v = (const float*)d_in[2];
    float* o = (float*)d_out;
    const size_t elems = (size_t)NHEAD * S_LEN * D_DIM;
    const size_t kvBytes = 2 * elems * sizeof(__bf16);                          // 16.8 MB
    const size_t partA = (size_t)NHEAD * 36 * PART_FLOATS * sizeof(float);      // ~38.9 MB
    const size_t partB = (size_t)512 * PART_FLOATS * sizeof(float);             // ~17.3 MB
    if (ws_size >= kvBytes + partA) {
        __bf16* Kb  = (__bf16*)d_ws;
        __bf16* Vtg = Kb + elems;
        float* Pp   = (float*)((char*)d_ws + kvBytes);
        convert_kv<<<dim3(32, 32), dim3(256), 0, stream>>>(k, v, Kb, Vtg);
        attn32<0><<<dim3(1280), dim3(256), 0, stream>>>(q, Kb, Vtg, o, Pp);
        combine<0><<<dim3(12, 32), dim3(256), 0, stream>>>(Pp, o);
    } else if (ws_size >= kvBytes + partB) {
        __bf16* Kb  = (__bf16*)d_ws;
        __bf16* Vtg = Kb + elems;
        float* Pp   = (float*)((char*)d_ws + kvBytes);
        convert_kv<<<dim3(32, 32), dim3(256), 0, stream>>>(k, v, Kb, Vtg);
        attn32<1><<<dim3(768), dim3(256), 0, stream>>>(q, Kb, Vtg, o, Pp);
        combine<1><<<dim3(8, 32), dim3(256), 0, stream>>>(Pp, o);
    } else {
        attn_fwd_fb<<<dim3(1024), dim3(256), 0, stream>>>(q, k, v, o);
    }
}

// Round 12
// 72.347 us; speedup vs baseline: 1.5715x; 1.5715x over previous
//
#include <hip/hip_runtime.h>

typedef __bf16 bf16x8 __attribute__((ext_vector_type(8)));
typedef float f32x4 __attribute__((ext_vector_type(4)));
typedef float f32x16 __attribute__((ext_vector_type(16)));

#define S_LEN 2048
#define D_DIM 64
#define NHEAD 32
#define PART_FLOATS 8448   // 128 m + 128 l + 128*64 acc

typedef __attribute__((address_space(1))) const void gas;
typedef __attribute__((address_space(3))) void las;

// job word: chunk(4b) | t0<<4 (5b) | nt<<9 (4b) | seg<<13 (2b)
#define J2(c, t0, nt, seg) ((unsigned short)((c) | ((t0) << 4) | ((nt) << 9) | ((seg) << 13)))

// MODE 0: 32 jobs/head, 8 CU-slots x 4 passes, each slot sums to exactly 34
// tiles (chunk c costs 2c+2 tiles; segments <= 12 tiles). JOBS4[slot*4+pass].
__device__ const unsigned short JOBS4[32] = {
    J2(11,0,12,0), J2(11,12,12,1), J2(3,0,8,0),   J2(0,0,2,0),
    J2(15,0,11,0), J2(15,11,11,1), J2(7,0,8,0),   J2(1,0,4,0),
    J2(10,0,11,0), J2(10,11,11,1), J2(5,0,6,0),   J2(5,6,6,1),
    J2(15,22,10,2),J2(14,0,10,0),  J2(8,0,9,0),   J2(4,0,5,0),
    J2(14,10,10,1),J2(14,20,10,2), J2(8,9,9,1),   J2(4,5,5,1),
    J2(13,0,10,0), J2(9,0,10,0),   J2(7,8,8,1),   J2(2,0,6,0),
    J2(9,10,10,1), J2(13,10,9,1),  J2(12,18,8,2), J2(6,0,7,0),
    J2(13,19,9,2), J2(12,0,9,0),   J2(12,9,9,1),  J2(6,7,7,1),
};
// partial-slot prefix for chunks 4..15 (nseg = 2 x8, 3 x4; total 28)
__device__ const int PRE[12]  = {0,2,4,6,8,10,12,14,16,19,22,25};
__device__ const int NSEG[12] = {2,2,2,2,2,2,2,2,3,3,3,3};

// MODE 1: 24 jobs/head, 8 CU-triples of 34 tiles (round-10 schedule, proven).
#define J(c, t0, nt) ((unsigned short)((c) | ((t0) << 4) | ((nt) << 9)))
__device__ const unsigned short TRIP[24] = {
    J(15,0,16), J(15,16,16), J(0,0,2),
    J(7,0,16),  J(13,0,14),  J(1,0,4),
    J(14,0,15), J(12,0,13),  J(2,0,6),
    J(14,15,15),J(10,0,11),  J(3,0,8),
    J(13,14,14),J(10,11,11), J(8,0,9),
    J(6,0,14),  J(9,0,10),   J(9,10,10),
    J(12,13,13),J(11,0,12),  J(8,9,9),
    J(11,12,12),J(5,0,12),   J(4,0,10),
};

// ---------------- pre-pass: K -> bf16 [h][s][d], V -> bf16 transposed [h][d][s] ----------------
__global__ __launch_bounds__(256) void convert_kv(const float* __restrict__ K,
                                                  const float* __restrict__ V,
                                                  __bf16* __restrict__ Kb,
                                                  __bf16* __restrict__ Vtg) {
    const int head = blockIdx.y;
    const int s0   = blockIdx.x * 64;
    const int tr   = threadIdx.x >> 2;
    const int tc   = (threadIdx.x & 3) << 4;
    const size_t ib = (size_t)head * (S_LEN * D_DIM) + (size_t)(s0 + tr) * D_DIM + tc;

    __shared__ __bf16 tb[64][72];

    {   // K: straight convert
        const float* kr = K + ib;
        f32x4 a = *(const f32x4*)kr, b = *(const f32x4*)(kr + 4),
              c = *(const f32x4*)(kr + 8), d = *(const f32x4*)(kr + 12);
        bf16x8 o0, o1;
        #pragma unroll
        for (int e = 0; e < 4; ++e) {
            o0[e] = (__bf16)a[e]; o0[e + 4] = (__bf16)b[e];
            o1[e] = (__bf16)c[e]; o1[e + 4] = (__bf16)d[e];
        }
        __bf16* ko = Kb + ib;
        *(bf16x8*)ko = o0; *(bf16x8*)(ko + 8) = o1;
    }
    {   // V: transpose 64x64 tile via LDS
        const float* vr = V + ib;
        f32x4 a = *(const f32x4*)vr, b = *(const f32x4*)(vr + 4),
              c = *(const f32x4*)(vr + 8), d = *(const f32x4*)(vr + 12);
        #pragma unroll
        for (int e = 0; e < 4; ++e) {
            tb[tc +  e][tr] = (__bf16)a[e];
            tb[tc + 4 + e][tr] = (__bf16)b[e];
            tb[tc + 8 + e][tr] = (__bf16)c[e];
            tb[tc + 12 + e][tr] = (__bf16)d[e];
        }
    }
    __syncthreads();
    {
        bf16x8 o0, o1;
        #pragma unroll
        for (int e = 0; e < 8; ++e) { o0[e] = tb[tr][tc + e]; o1[e] = tb[tr][tc + 8 + e]; }
        __bf16* vo = Vtg + (size_t)head * (D_DIM * S_LEN) + (size_t)tr * S_LEN + s0 + tc;
        *(bf16x8*)vo = o0; *(bf16x8*)(vo + 8) = o1;
    }
}

// ---------------- main: 32x32 MFMA flash attention, in-register P (T12) ----------------
// MODE 0: 1024 blocks (4/CU), JOBS4. MODE 1: 768 blocks (3/CU), TRIP.
template <int MODE>
__global__ __launch_bounds__(256, MODE == 0 ? 4 : 3)
void attn32(const float* __restrict__ Q,
            const __bf16* __restrict__ Kb,
            const __bf16* __restrict__ Vg,
            float* __restrict__ O,
            float* __restrict__ Pp) {
    const int b    = blockIdx.x;
    const int xcd  = b & 7;
    const int cu   = (b >> 3) & 31;
    const int pass = b >> 8;                  // MODE0: 0..3, MODE1: 0..2
    const int head = xcd * 4 + (cu >> 3);     // 4 heads per XCD
    const unsigned short jw = (MODE == 0) ? JOBS4[(cu & 7) * 4 + pass]
                                          : TRIP[(cu & 7) * 3 + pass];
    const int chunk = jw & 15;                // 128-row q-chunk
    const int t0    = (jw >> 4) & 31;         // first 64-key tile
    const int nt    = (jw >> 9) & 15;         // tile count
    const int seg   = jw >> 13;               // segment index within chunk (MODE0)

    const int tid  = threadIdx.x;
    const int wave = tid >> 6;
    const int lane = tid & 63;
    const int l31  = lane & 31;
    const int hi   = lane >> 5;
    const int sw31 = (l31 & 7) << 3;

    const int q0w = chunk * 128 + wave * 32;  // wave owns q rows q0w..q0w+31
    const size_t qbase = (size_t)head * (S_LEN * D_DIM);
    const size_t vbase = (size_t)head * (D_DIM * S_LEN);
    const float qscale = 0.125f * 1.44269504088896340736f;   // D^-0.5 * log2(e)

    __shared__ __align__(16) __bf16 Klds[2][64][64];   // [buf][key][d], 16B-unit col ^ (key&7)
    __shared__ __align__(16) __bf16 Vt[2][64][64];     // [buf][d][key], 16B-unit col ^ (d&7)

    // per-lane pre-swizzled gload_lds source offsets
    const int xsw = (lane & 7) ^ ((lane >> 3) & 7);
    const size_t kOff = (size_t)(lane >> 3) * D_DIM + (size_t)xsw * 8;
    const size_t vOff = (size_t)(lane >> 3) * S_LEN + (size_t)xsw * 8;
    const __bf16* kgw = Kb + qbase + (size_t)(wave * 16) * D_DIM + kOff;
    const __bf16* vgw = Vg + vbase + (size_t)(wave * 16) * S_LEN + vOff;

    // ---- Q B-frags (swapped QK^T): col=q=l31, k-dim d = kd*16 + hi*8 + e ----
    bf16x8 qf[4];
    {
        const float* qrow = Q + qbase + (size_t)(q0w + l31) * D_DIM + hi * 8;
        #pragma unroll
        for (int kd = 0; kd < 4; ++kd) {
            f32x4 a = *(const f32x4*)(qrow + kd * 16);
            f32x4 c = *(const f32x4*)(qrow + kd * 16 + 4);
            bf16x8 t;
            #pragma unroll
            for (int e = 0; e < 4; ++e) { t[e] = (__bf16)(a[e] * qscale); t[e + 4] = (__bf16)(c[e] * qscale); }
            qf[kd] = t;
        }
    }

    f32x16 acc0, acc1;                        // O[q=crow(r,hi)][d = l31 (+32 for acc1)]
    #pragma unroll
    for (int r = 0; r < 16; ++r) { acc0[r] = 0.f; acc1[r] = 0.f; }
    float m_r = -1e30f, l_r = 0.f;            // per-lane: q-row = q0w + l31

    auto stage = [&](int kv0, int bufi) {
        const __bf16* kg = kgw + (size_t)kv0 * D_DIM;
        const __bf16* vg = vgw + kv0;
        __builtin_amdgcn_global_load_lds((gas*)kg,               (las*)&Klds[bufi][wave * 16][0],     16, 0, 0);
        __builtin_amdgcn_global_load_lds((gas*)(kg + 8 * D_DIM), (las*)&Klds[bufi][wave * 16 + 8][0], 16, 0, 0);
        __builtin_amdgcn_global_load_lds((gas*)vg,               (las*)&Vt[bufi][wave * 16][0],       16, 0, 0);
        __builtin_amdgcn_global_load_lds((gas*)(vg + 8 * S_LEN), (las*)&Vt[bufi][wave * 16 + 8][0],   16, 0, 0);
    };
    auto cvtpk = [](float lo, float hh) {
        unsigned int r;
        asm("v_cvt_pk_bf16_f32 %0, %1, %2" : "=v"(r) : "v"(lo), "v"(hh));
        return r;
    };

    stage(t0 << 6, 0);

    for (int it = 0; it < nt; ++it) {
        const int cur = it & 1;
        asm volatile("s_waitcnt vmcnt(0)" ::: "memory");
        __syncthreads();                      // buf[cur] fully staged by all waves

        if (it + 1 < nt) stage((t0 + it + 1) << 6, cur ^ 1);
        const int kv0 = (t0 + it) << 6;

        if (kv0 <= q0w + 31) {                // wave has unmasked work this tile
            // ---- S^T = K Q^T (32x32): lane holds 32 scores of q-row q0w+l31 ----
            f32x16 s0, s1;
            #pragma unroll
            for (int r = 0; r < 16; ++r) { s0[r] = 0.f; s1[r] = 0.f; }
            __builtin_amdgcn_s_setprio(1);
            #pragma unroll
            for (int kd = 0; kd < 4; ++kd) {
                bf16x8 kf0 = *(const bf16x8*)&Klds[cur][l31][(kd * 16 + hi * 8) ^ sw31];
                bf16x8 kf1 = *(const bf16x8*)&Klds[cur][32 + l31][(kd * 16 + hi * 8) ^ sw31];
                s0 = __builtin_amdgcn_mfma_f32_32x32x16_bf16(kf0, qf[kd], s0, 0, 0, 0);
                s1 = __builtin_amdgcn_mfma_f32_32x32x16_bf16(kf1, qf[kd], s1, 0, 0, 0);
            }
            __builtin_amdgcn_s_setprio(0);

            // ---- causal mask (diagonal-straddling tiles only) ----
            if (kv0 + 63 > q0w) {
                const int qg = q0w + l31;
                #pragma unroll
                for (int r = 0; r < 16; ++r) {
                    const int cr = (r & 3) + 8 * (r >> 2) + 4 * hi;
                    if (kv0 + cr > qg)      s0[r] = -1e30f;
                    if (kv0 + 32 + cr > qg) s1[r] = -1e30f;
                }
            }

            // ---- in-lane online softmax; tree reductions ----
            float t[16];
            #pragma unroll
            for (int r = 0; r < 16; ++r) t[r] = fmaxf(s0[r], s1[r]);
            #pragma unroll
            for (int off = 8; off >= 1; off >>= 1)
                #pragma unroll
                for (int r = 0; r < 16; ++r) if (r < off) t[r] = fmaxf(t[r], t[r + off]);
            float mm = fmaxf(t[0], __shfl_xor(t[0], 32));
            if (!__all(mm - m_r <= 8.0f)) {   // defer-max: rescale rarely
                const float mn = fmaxf(m_r, mm);
                const float f = exp2f(m_r - mn);
                m_r = mn;
                l_r *= f;
                #pragma unroll
                for (int r = 0; r < 16; ++r) {
                    const float fr = __shfl(f, (r & 3) + 8 * (r >> 2) + 4 * hi);
                    acc0[r] *= fr; acc1[r] *= fr;
                }
            }
            float u[16];
            #pragma unroll
            for (int r = 0; r < 16; ++r) {
                s0[r] = exp2f(s0[r] - m_r);
                s1[r] = exp2f(s1[r] - m_r);
                u[r] = s0[r] + s1[r];
            }
            #pragma unroll
            for (int off = 8; off >= 1; off >>= 1)
                #pragma unroll
                for (int r = 0; r < 16; ++r) if (r < off) u[r] += u[r + off];
            l_r += u[0] + __shfl_xor(u[0], 32);

            // ---- P -> A-frags in-register (T12: cvt_pk + permlane32_swap), then PV ----
            __builtin_amdgcn_s_setprio(1);
            {   // keys kv0..+31
                unsigned int w01 = cvtpk(s0[0],  s0[1]),  w23 = cvtpk(s0[2],  s0[3]);
                unsigned int w45 = cvtpk(s0[4],  s0[5]),  w67 = cvtpk(s0[6],  s0[7]);
                unsigned int w89 = cvtpk(s0[8],  s0[9]),  wab = cvtpk(s0[10], s0[11]);
                unsigned int wcd = cvtpk(s0[12], s0[13]), wef = cvtpk(s0[14], s0[15]);
                asm("v_permlane32_swap_b32 %0, %1" : "+v"(w01), "+v"(w45));
                asm("v_permlane32_swap_b32 %0, %1" : "+v"(w23), "+v"(w67));
                asm("v_permlane32_swap_b32 %0, %1" : "+v"(w89), "+v"(wcd));
                asm("v_permlane32_swap_b32 %0, %1" : "+v"(wab), "+v"(wef));
                union { unsigned int u[4]; bf16x8 v; } f0 = {{w01, w23, w45, w67}};
                union { unsigned int u[4]; bf16x8 v; } f1 = {{w89, wab, wcd, wef}};
                bf16x8 v00 = *(const bf16x8*)&Vt[cur][l31][(hi * 8) ^ sw31];
                bf16x8 v01 = *(const bf16x8*)&Vt[cur][32 + l31][(hi * 8) ^ sw31];
                acc0 = __builtin_amdgcn_mfma_f32_32x32x16_bf16(f0.v, v00, acc0, 0, 0, 0);
                acc1 = __builtin_amdgcn_mfma_f32_32x32x16_bf16(f0.v, v01, acc1, 0, 0, 0);
                bf16x8 v10 = *(const bf16x8*)&Vt[cur][l31][(16 + hi * 8) ^ sw31];
                bf16x8 v11 = *(const bf16x8*)&Vt[cur][32 + l31][(16 + hi * 8) ^ sw31];
                acc0 = __builtin_amdgcn_mfma_f32_32x32x16_bf16(f1.v, v10, acc0, 0, 0, 0);
                acc1 = __builtin_amdgcn_mfma_f32_32x32x16_bf16(f1.v, v11, acc1, 0, 0, 0);
            }
            {   // keys kv0+32..+63
                unsigned int w01 = cvtpk(s1[0],  s1[1]),  w23 = cvtpk(s1[2],  s1[3]);
                unsigned int w45 = cvtpk(s1[4],  s1[5]),  w67 = cvtpk(s1[6],  s1[7]);
                unsigned int w89 = cvtpk(s1[8],  s1[9]),  wab = cvtpk(s1[10], s1[11]);
                unsigned int wcd = cvtpk(s1[12], s1[13]), wef = cvtpk(s1[14], s1[15]);
                asm("v_permlane32_swap_b32 %0, %1" : "+v"(w01), "+v"(w45));
                asm("v_permlane32_swap_b32 %0, %1" : "+v"(w23), "+v"(w67));
                asm("v_permlane32_swap_b32 %0, %1" : "+v"(w89), "+v"(wcd));
                asm("v_permlane32_swap_b32 %0, %1" : "+v"(wab), "+v"(wef));
                union { unsigned int u[4]; bf16x8 v; } f2 = {{w01, w23, w45, w67}};
                union { unsigned int u[4]; bf16x8 v; } f3 = {{w89, wab, wcd, wef}};
                bf16x8 v20 = *(const bf16x8*)&Vt[cur][l31][(32 + hi * 8) ^ sw31];
                bf16x8 v21 = *(const bf16x8*)&Vt[cur][32 + l31][(32 + hi * 8) ^ sw31];
                acc0 = __builtin_amdgcn_mfma_f32_32x32x16_bf16(f2.v, v20, acc0, 0, 0, 0);
                acc1 = __builtin_amdgcn_mfma_f32_32x32x16_bf16(f2.v, v21, acc1, 0, 0, 0);
                bf16x8 v30 = *(const bf16x8*)&Vt[cur][l31][(48 + hi * 8) ^ sw31];
                bf16x8 v31 = *(const bf16x8*)&Vt[cur][32 + l31][(48 + hi * 8) ^ sw31];
                acc0 = __builtin_amdgcn_mfma_f32_32x32x16_bf16(f3.v, v30, acc0, 0, 0, 0);
                acc1 = __builtin_amdgcn_mfma_f32_32x32x16_bf16(f3.v, v31, acc1, 0, 0, 0);
            }
            __builtin_amdgcn_s_setprio(0);
        }
    }

    // ---- epilogue ----
    const bool direct = (MODE == 0) ? (chunk < 4) : (chunk < 8);
    if (direct) {                             // unsplit chunk: O = acc / l
        const float inv_own = 1.0f / l_r;
        float* ob = O + qbase + (size_t)(chunk * 128 + wave * 32) * D_DIM + l31;
        #pragma unroll
        for (int r = 0; r < 16; ++r) {
            const int cr = (r & 3) + 8 * (r >> 2) + 4 * hi;
            const float inv = __shfl(inv_own, cr);
            ob[(size_t)cr * D_DIM]      = acc0[r] * inv;
            ob[(size_t)cr * D_DIM + 32] = acc1[r] * inv;
        }
    } else {                                  // split segment: raw fp32 partials
        size_t slot;
        if (MODE == 0) slot = (size_t)head * 28 + PRE[chunk - 4] + seg;
        else           slot = (size_t)((head * 8 + (chunk - 8)) * 2 + (t0 != 0 ? 1 : 0));
        float* pp = Pp + slot * PART_FLOATS;
        if (hi == 0) {
            pp[wave * 32 + l31] = m_r;
            pp[128 + wave * 32 + l31] = l_r;
        }
        float* pb = pp + 256 + (size_t)(wave * 32) * 64 + l31;
        #pragma unroll
        for (int r = 0; r < 16; ++r) {
            const int cr = (r & 3) + 8 * (r >> 2) + 4 * hi;
            pb[(size_t)cr * 64]      = acc0[r];
            pb[(size_t)cr * 64 + 32] = acc1[r];
        }
    }
}

// ---------------- combine ----------------
// MODE 0: chunks 4..15, 2..3 segments each. MODE 1: chunks 8..15, 2 segments.
template <int MODE>
__global__ __launch_bounds__(256) void combine(const float* __restrict__ Pp,
                                               float* __restrict__ O) {
    const int head = blockIdx.y;
    const int bx   = blockIdx.x;
    const int ch   = (MODE == 0) ? (4 + bx) : (8 + bx);
    const int ns   = (MODE == 0) ? NSEG[bx] : 2;
    const size_t base = (MODE == 0) ? ((size_t)head * 28 + PRE[bx])
                                    : (size_t)((head * 8 + bx) * 2);
    const int row = threadIdx.x >> 1;          // 0..127
    const int c0  = (threadIdx.x & 1) << 5;    // 0, 32

    float m[3], l[3], w[3];
    float M = -1e30f;
    #pragma unroll
    for (int s = 0; s < 3; ++s)
        if (s < ns) {
            const float* P = Pp + (base + s) * PART_FLOATS;
            m[s] = P[row]; l[s] = P[128 + row];
            M = fmaxf(M, m[s]);
        }
    float L = 0.f;
    #pragma unroll
    for (int s = 0; s < 3; ++s)
        if (s < ns) { w[s] = exp2f(m[s] - M); L += l[s] * w[s]; }
    const float inv = 1.0f / L;

    float* o = O + (size_t)head * (S_LEN * D_DIM) + (size_t)(ch * 128 + row) * D_DIM + c0;
    #pragma unroll
    for (int i = 0; i < 8; ++i) {
        f32x4 vo = (f32x4){0.f, 0.f, 0.f, 0.f};
        #pragma unroll
        for (int s = 0; s < 3; ++s)
            if (s < ns) {
                const float* a = Pp + (base + s) * PART_FLOATS + 256 + (size_t)row * 64 + c0;
                f32x4 va = *(const f32x4*)(a + 4 * i);
                #pragma unroll
                for (int e = 0; e < 4; ++e) vo[e] += va[e] * w[s];
            }
        #pragma unroll
        for (int e = 0; e < 4; ++e) vo[e] *= inv;
        *(f32x4*)(o + 4 * i) = vo;
    }
}

// ---------------- fallback (fp32 in-kernel staging, proven) if ws too small ----------------
__global__ __launch_bounds__(256, 4) void attn_fwd_fb(const float* __restrict__ Q,
                                                      const float* __restrict__ K,
                                                      const float* __restrict__ V,
                                                      float* __restrict__ O) {
    const int b    = blockIdx.x;
    const int xcd  = b & 7;
    const int cs   = (b >> 3) & 31;
    const int j    = b >> 8;
    const int head = xcd * 4 + (cs >> 3);
    const int slot = cs & 7;
    const int chunk = (j == 0) ? slot : (j == 1) ? (31 - slot)
                    : (j == 2) ? (slot + 8) : (23 - slot);

    const int tid  = threadIdx.x;
    const int wave = tid >> 6;
    const int lane = tid & 63;
    const int l15  = lane & 15;
    const int lhi  = lane >> 4;

    const int q0 = chunk * 64 + wave * 16;
    const size_t base = (size_t)head * (S_LEN * D_DIM);
    const float qscale = 0.125f * 1.44269504088896340736f;

    __shared__ __align__(16) __bf16 Klds[2][64][64];
    __shared__ __align__(16) __bf16 Vt[2][64][64];
    __shared__ __align__(16) __bf16 Plds[4][16][64];

    const int rk = tid >> 2;
    const int ck = (tid & 3) << 4;
    const int kp = tid & 31;
    const int dc = tid >> 5;
    const int swk = (rk & 7) << 3;

    bf16x8 qf[2];
    {
        const float* qrow = Q + base + (size_t)(q0 + l15) * D_DIM + lhi * 8;
        #pragma unroll
        for (int h = 0; h < 2; ++h) {
            f32x4 a = *(const f32x4*)(qrow + h * 32);
            f32x4 bq = *(const f32x4*)(qrow + h * 32 + 4);
            bf16x8 t;
            #pragma unroll
            for (int e = 0; e < 4; ++e) { t[e] = (__bf16)(a[e] * qscale); t[e + 4] = (__bf16)(bq[e] * qscale); }
            qf[h] = t;
        }
    }

    f32x4 acc[4];
    #pragma unroll
    for (int td = 0; td < 4; ++td) acc[td] = (f32x4){0.f, 0.f, 0.f, 0.f};
    float m_r = -1e30f, l_r = 0.f;

    f32x4 pk[4], pva[2], pvb[2];
    {
        const float* ks = K + base + (size_t)rk * D_DIM + ck;
        #pragma unroll
        for (int i = 0; i < 4; ++i) pk[i] = *(const f32x4*)(ks + 4 * i);
        const float* v0 = V + base + (size_t)(2 * kp) * D_DIM + dc * 8;
        pva[0] = *(const f32x4*)v0;           pva[1] = *(const f32x4*)(v0 + 4);
        pvb[0] = *(const f32x4*)(v0 + D_DIM); pvb[1] = *(const f32x4*)(v0 + D_DIM + 4);
        bf16x8 k0, k1;
        #pragma unroll
        for (int e = 0; e < 4; ++e) {
            k0[e] = (__bf16)pk[0][e]; k0[e + 4] = (__bf16)pk[1][e];
            k1[e] = (__bf16)pk[2][e]; k1[e + 4] = (__bf16)pk[3][e];
        }
        *(bf16x8*)&Klds[0][rk][ck ^ swk] = k0;
        *(bf16x8*)&Klds[0][rk][(ck + 8) ^ swk] = k1;
        #pragma unroll
        for (int jj = 0; jj < 8; ++jj) {
            const int d = dc * 8 + jj;
            const float av = (jj < 4) ? pva[0][jj & 3] : pva[1][jj & 3];
            const float bv = (jj < 4) ? pvb[0][jj & 3] : pvb[1][jj & 3];
            union { __bf16 h[2]; unsigned int u; } t;
            t.h[0] = (__bf16)av; t.h[1] = (__bf16)bv;
            *(unsigned int*)&Vt[0][d][(2 * kp) ^ ((d & 7) << 3)] = t.u;
        }
    }

    const int nt = chunk + 1;
    for (int kt = 0; kt < nt; ++kt) {
        const int cur = kt & 1;
        __syncthreads();
        const bool pre = (kt + 1 < nt);
        if (pre) {
            const int kv1 = (kt + 1) << 6;
            const float* ks = K + base + (size_t)(kv1 + rk) * D_DIM + ck;
            #pragma unroll
            for (int i = 0; i < 4; ++i) pk[i] = *(const f32x4*)(ks + 4 * i);
            const float* v0 = V + base + (size_t)(kv1 + 2 * kp) * D_DIM + dc * 8;
            pva[0] = *(const f32x4*)v0;           pva[1] = *(const f32x4*)(v0 + 4);
            pvb[0] = *(const f32x4*)(v0 + D_DIM); pvb[1] = *(const f32x4*)(v0 + D_DIM + 4);
        }

        f32x4 s[4];
        #pragma unroll
        for (int ct = 0; ct < 4; ++ct) s[ct] = (f32x4){0.f, 0.f, 0.f, 0.f};
        #pragma unroll
        for (int h = 0; h < 2; ++h) {
            #pragma unroll
            for (int ct = 0; ct < 4; ++ct) {
                const int krow = ct * 16 + l15;
                bf16x8 kf = *(const bf16x8*)&Klds[cur][krow][(h * 32 + lhi * 8) ^ ((l15 & 7) << 3)];
                s[ct] = __builtin_amdgcn_mfma_f32_16x16x32_bf16(kf, qf[h], s[ct], 0, 0, 0);
            }
        }

        if (kt == nt - 1) {
            const int kv0 = kt << 6;
            const int qg = q0 + l15;
            #pragma unroll
            for (int ct = 0; ct < 4; ++ct)
                #pragma unroll
                for (int r = 0; r < 4; ++r) {
                    const int kg = kv0 + ct * 16 + lhi * 4 + r;
                    if (kg > qg) s[ct][r] = -1e30f;
                }
        }

        float mm = fmaxf(fmaxf(fmaxf(s[0][0], s[0][1]), fmaxf(s[0][2], s[0][3])),
                         fmaxf(fmaxf(s[1][0], s[1][1]), fmaxf(s[1][2], s[1][3])));
        mm = fmaxf(mm, fmaxf(fmaxf(fmaxf(s[2][0], s[2][1]), fmaxf(s[2][2], s[2][3])),
                             fmaxf(fmaxf(s[3][0], s[3][1]), fmaxf(s[3][2], s[3][3]))));
        mm = fmaxf(mm, __shfl_xor(mm, 16));
        mm = fmaxf(mm, __shfl_xor(mm, 32));
        if (!__all(mm - m_r <= 8.0f)) {
            const float mn = fmaxf(m_r, mm);
            const float f = exp2f(m_r - mn);
            m_r = mn;
            l_r *= f;
            #pragma unroll
            for (int r = 0; r < 4; ++r) {
                const float fr = __shfl(f, lhi * 4 + r);
                #pragma unroll
                for (int td = 0; td < 4; ++td) acc[td][r] *= fr;
            }
        }
        float ps = 0.f;
        #pragma unroll
        for (int ct = 0; ct < 4; ++ct)
            #pragma unroll
            for (int r = 0; r < 4; ++r) {
                const float p = exp2f(s[ct][r] - m_r);
                s[ct][r] = p;
                ps += p;
            }
        ps += __shfl_xor(ps, 16);
        ps += __shfl_xor(ps, 32);
        l_r += ps;

        #pragma unroll
        for (int ct = 0; ct < 4; ++ct) {
            union { __bf16 h[4]; unsigned long long u; } pw;
            #pragma unroll
            for (int r = 0; r < 4; ++r) pw.h[r] = (__bf16)s[ct][r];
            *(unsigned long long*)&Plds[wave][l15][(ct * 16 + lhi * 4) ^ ((l15 & 7) << 3)] = pw.u;
        }
        asm volatile("s_waitcnt lgkmcnt(0)" ::: "memory");
        bf16x8 pf[2];
        #pragma unroll
        for (int kh = 0; kh < 2; ++kh)
            pf[kh] = *(const bf16x8*)&Plds[wave][l15][(kh * 32 + lhi * 8) ^ ((l15 & 7) << 3)];
        asm volatile("" ::: "memory");

        #pragma unroll
        for (int kh = 0; kh < 2; ++kh) {
            #pragma unroll
            for (int td = 0; td < 4; ++td) {
                const int vrow = td * 16 + l15;
                bf16x8 vf = *(const bf16x8*)&Vt[cur][vrow][(kh * 32 + lhi * 8) ^ ((vrow & 7) << 3)];
                acc[td] = __builtin_amdgcn_mfma_f32_16x16x32_bf16(pf[kh], vf, acc[td], 0, 0, 0);
            }
        }

        if (pre) {
            const int nxt = cur ^ 1;
            bf16x8 k0, k1;
            #pragma unroll
            for (int e = 0; e < 4; ++e) {
                k0[e] = (__bf16)pk[0][e]; k0[e + 4] = (__bf16)pk[1][e];
                k1[e] = (__bf16)pk[2][e]; k1[e + 4] = (__bf16)pk[3][e];
            }
            *(bf16x8*)&Klds[nxt][rk][ck ^ swk] = k0;
            *(bf16x8*)&Klds[nxt][rk][(ck + 8) ^ swk] = k1;
            #pragma unroll
            for (int jj = 0; jj < 8; ++jj) {
                const int d = dc * 8 + jj;
                const float av = (jj < 4) ? pva[0][jj & 3] : pva[1][jj & 3];
                const float bv = (jj < 4) ? pvb[0][jj & 3] : pvb[1][jj & 3];
                union { __bf16 h[2]; unsigned int u; } t;
                t.h[0] = (__bf16)av; t.h[1] = (__bf16)bv;
                *(unsigned int*)&Vt[nxt][d][(2 * kp) ^ ((d & 7) << 3)] = t.u;
            }
        }
    }

    float* orow = O + base + (size_t)q0 * D_DIM;
    #pragma unroll
    for (int r = 0; r < 4; ++r) {
        const float inv = 1.0f / __shfl(l_r, lhi * 4 + r);
        #pragma unroll
        for (int td = 0; td < 4; ++td)
            orow[(size_t)(lhi * 4 + r) * D_DIM + td * 16 + l15] = acc[td][r] * inv;
    }
}

extern "C" void kernel_launch(void* const* d_in, const int* in_sizes, int n_in,
                              void* d_out, int out_size, void* d_ws, size_t ws_size,
                              hipStream_t stream) {
    const float* q = (const float*)d_in[0];
    const float* k = (const float*)d_in[1];
    const float* v = (const float*)d_in[2];
    float* o = (float*)d_out;
    const size_t elems = (size_t)NHEAD * S_LEN * D_DIM;
    const size_t kvBytes = 2 * elems * sizeof(__bf16);                          // 16.8 MB
    const size_t partA = (size_t)NHEAD * 28 * PART_FLOATS * sizeof(float);      // ~30.3 MB
    const size_t partB = (size_t)512 * PART_FLOATS * sizeof(float);             // ~17.3 MB
    if (ws_size >= kvBytes + partA) {
        __bf16* Kb  = (__bf16*)d_ws;
        __bf16* Vtg = Kb + elems;
        float* Pp   = (float*)((char*)d_ws + kvBytes);
        convert_kv<<<dim3(32, 32), dim3(256), 0, stream>>>(k, v, Kb, Vtg);
        attn32<0><<<dim3(1024), dim3(256), 0, stream>>>(q, Kb, Vtg, o, Pp);
        combine<0><<<dim3(12, 32), dim3(256), 0, stream>>>(Pp, o);
    } else if (ws_size >= kvBytes + partB) {
        __bf16* Kb  = (__bf16*)d_ws;
        __bf16* Vtg = Kb + elems;
        float* Pp   = (float*)((char*)d_ws + kvBytes);
        convert_kv<<<dim3(32, 32), dim3(256), 0, stream>>>(k, v, Kb, Vtg);
        attn32<1><<<dim3(768), dim3(256), 0, stream>>>(q, Kb, Vtg, o, Pp);
        combine<1><<<dim3(8, 32), dim3(256), 0, stream>>>(Pp, o);
    } else {
        attn_fwd_fb<<<dim3(1024), dim3(256), 0, stream>>>(q, k, v, o);
    }
}